// Round 1
// 109.575 us; speedup vs baseline: 1.0454x; 1.0454x over previous
//
#include <hip/hip_runtime.h>
#include <stdint.h>

#define SEQ   2048
#define DM    512
#define NHEAD 8
#define DKH   64
#define WIN   64
#define NEGV  -1000000000.0f

typedef __attribute__((ext_vector_type(8))) short          short8;
typedef __attribute__((ext_vector_type(4))) float          float4v;
typedef __attribute__((ext_vector_type(8))) unsigned short ushort8v;

__device__ __forceinline__ unsigned short f2bf(float x) {
    uint32_t u = __float_as_uint(x);
    uint32_t r = (u + 0x7FFFu + ((u >> 16) & 1u)) >> 16;
    return (unsigned short)r;
}
__device__ __forceinline__ float bf2f(unsigned short u) {
    return __uint_as_float(((uint32_t)u) << 16);
}

// async 16B global -> LDS (wave-uniform base + lane*16 pattern)
__device__ __forceinline__ void async_cp16(const void* g, void* lds) {
    __builtin_amdgcn_global_load_lds(
        (const __attribute__((address_space(1))) unsigned int*)(uintptr_t)g,
        (__attribute__((address_space(3))) unsigned int*)(uint32_t)(uintptr_t)lds,
        16, 0, 0);
}

// ---------------------------------------------------------------------------
// Fused f32 -> bf16 cast of q,k,v (1M each) + Wq,Wk,Wv,Wo (256K each).
// ---------------------------------------------------------------------------
__global__ __launch_bounds__(256)
void cast7_kernel(const float* __restrict__ q, const float* __restrict__ k,
                  const float* __restrict__ v, const float* __restrict__ wq,
                  const float* __restrict__ wk, const float* __restrict__ wv,
                  const float* __restrict__ wo, unsigned short* __restrict__ dst)
{
    int g = (blockIdx.x * 256 + threadIdx.x) * 8;   // < 4194304
    const float* src; int off;
    if      (g < 1048576) { src = q;  off = g; }
    else if (g < 2097152) { src = k;  off = g - 1048576; }
    else if (g < 3145728) { src = v;  off = g - 2097152; }
    else if (g < 3407872) { src = wq; off = g - 3145728; }
    else if (g < 3670016) { src = wk; off = g - 3407872; }
    else if (g < 3932160) { src = wv; off = g - 3670016; }
    else                  { src = wo; off = g - 3932160; }
    float4 x0 = *(const float4*)(src + off);
    float4 x1 = *(const float4*)(src + off + 4);
    ushort8v o;
    o[0] = f2bf(x0.x); o[1] = f2bf(x0.y); o[2] = f2bf(x0.z); o[3] = f2bf(x0.w);
    o[4] = f2bf(x1.x); o[5] = f2bf(x1.y); o[6] = f2bf(x1.z); o[7] = f2bf(x1.w);
    *(ushort8v*)(dst + g) = o;
}

// ---------------------------------------------------------------------------
// bf16 MFMA NT GEMM: C[m,n] = sum_k A[m,k]*B[n,k] (+bias[n]).
// OUT_BF16 selects bf16 or f32 output. 128x128 tile, 256 thr = 4 waves.
// 2-phase double-buffered K-loop (T3-minimum): stage tile t+1's
// global_load_lds BEFORE computing tile t, so the vmcnt(0) drain inside the
// single end-of-iteration __syncthreads() overlaps the ds_read+MFMA phase.
// At <=1 block/CU there is no cross-block TLP; this ILP is the only latency
// hiding available.
// ---------------------------------------------------------------------------
template<bool BIAS, bool OUT_BF16>
__device__ __forceinline__ void gemm_mfma_body(const unsigned short* __restrict__ A,
                                               const unsigned short* __restrict__ B,
                                               const float* __restrict__ bias,
                                               void* __restrict__ Cv)
{
    __shared__ __align__(16) unsigned short As[2][128 * 32];
    __shared__ __align__(16) unsigned short Bs[2][128 * 32];

    const int tid  = threadIdx.x;
    const int m0   = blockIdx.x * 128;
    const int n0   = blockIdx.y * 128;
    const int lane = tid & 63;
    const int wave = tid >> 6;
    const int wm   = (wave >> 1) * 64;
    const int wn   = (wave & 1) * 64;
    const int lm   = lane & 15;
    const int lk   = (lane >> 4) * 8;

    float4v acc[4][4] = {};

    // prologue: stage k0 = 0 into buffer 0 (cold HBM latency paid once)
    #pragma unroll
    for (int h = 0; h < 2; h++) {
        int c  = tid + h * 256;
        int rr = c >> 2;
        int kk = (c & 3) * 8;
        async_cp16(A + (size_t)(m0 + rr) * 512 + kk, &As[0][c * 8]);
        async_cp16(B + (size_t)(n0 + rr) * 512 + kk, &Bs[0][c * 8]);
    }
    __syncthreads();

    for (int t = 0; t < 16; ++t) {
        const int cur = t & 1;
        if (t < 15) {
            const int k0 = (t + 1) * 32;
            #pragma unroll
            for (int h = 0; h < 2; h++) {
                int c  = tid + h * 256;
                int rr = c >> 2;
                int kk = (c & 3) * 8;
                async_cp16(A + (size_t)(m0 + rr) * 512 + k0 + kk, &As[cur ^ 1][c * 8]);
                async_cp16(B + (size_t)(n0 + rr) * 512 + k0 + kk, &Bs[cur ^ 1][c * 8]);
            }
        }

        short8 av[4], bv[4];
        #pragma unroll
        for (int mt = 0; mt < 4; mt++)
            av[mt] = *(const short8*)(&As[cur][(wm + mt * 16 + lm) * 32 + lk]);
        #pragma unroll
        for (int nt = 0; nt < 4; nt++)
            bv[nt] = *(const short8*)(&Bs[cur][(wn + nt * 16 + lm) * 32 + lk]);
        #pragma unroll
        for (int mt = 0; mt < 4; mt++)
            #pragma unroll
            for (int nt = 0; nt < 4; nt++)
                acc[mt][nt] = __builtin_amdgcn_mfma_f32_16x16x32_bf16(
                    av[mt], bv[nt], acc[mt][nt], 0, 0, 0);

        // vmcnt(0) here waits on the t+1 stage loads, which have had the whole
        // ds_read+MFMA phase above to land; also guarantees all waves consumed
        // buffer `cur` before iteration t+1 overwrites it.
        __syncthreads();
    }

    const int r0 = (lane >> 4) * 4;
    const int cn = lane & 15;
    #pragma unroll
    for (int nt = 0; nt < 4; nt++) {
        int gcol = n0 + wn + nt * 16 + cn;
        float b = BIAS ? bias[gcol] : 0.f;
        #pragma unroll
        for (int mt = 0; mt < 4; mt++) {
            int grow = m0 + wm + mt * 16 + r0;
            #pragma unroll
            for (int reg = 0; reg < 4; reg++) {
                float val = acc[mt][nt][reg] + b;
                if (OUT_BF16)
                    ((unsigned short*)Cv)[(size_t)(grow + reg) * 512 + gcol] = f2bf(val);
                else
                    ((float*)Cv)[(size_t)(grow + reg) * 512 + gcol] = val;
            }
        }
    }
}

__global__ __launch_bounds__(256)
void qkv_gemm_kernel(const unsigned short* __restrict__ qb,
                     const unsigned short* __restrict__ kb,
                     const unsigned short* __restrict__ vb,
                     const unsigned short* __restrict__ wqb,
                     const unsigned short* __restrict__ wkb,
                     const unsigned short* __restrict__ wvb,
                     unsigned short* __restrict__ Qp, unsigned short* __restrict__ Kp,
                     unsigned short* __restrict__ Vp)
{
    const unsigned short *A, *B; unsigned short* C;
    if (blockIdx.z == 0)      { A = qb; B = wqb; C = Qp; }
    else if (blockIdx.z == 1) { A = kb; B = wkb; C = Kp; }
    else                      { A = vb; B = wvb; C = Vp; }
    gemm_mfma_body<false, true>(A, B, nullptr, C);
}

__global__ __launch_bounds__(256)
void out_gemm_kernel(const unsigned short* __restrict__ ctxb,
                     const unsigned short* __restrict__ wob,
                     const float* __restrict__ bo, float* __restrict__ out)
{
    gemm_mfma_body<true, false>(ctxb, wob, bo, out);
}

// ---------------------------------------------------------------------------
// MFMA windowed attention. Block = 64 queries x 1 head, 256 thr = 4 waves.
// Wave w owns queries q0+w*16..+15 and local key rows w*16..w*16+79.
// Vt stride = 152 ushorts (304B = 19x16B aligned; 2-way bank alias = free).
// Keys 128..151 explicitly zeroed: wave 3's PV reads reach key 143 with
// zero P operands — uninit LDS there was the r4/r5 NaN source (0*NaN=NaN).
// ---------------------------------------------------------------------------
#define VTS 152

__global__ __launch_bounds__(256)
void attn_kernel(const unsigned short* __restrict__ Qp,
                 const unsigned short* __restrict__ Kp,
                 const unsigned short* __restrict__ Vp,
                 unsigned short* __restrict__ ctxb,
                 float* __restrict__ attnw)
{
    __shared__ __align__(16) unsigned short Qs[64 * 72];    // [q_local][64 k]
    __shared__ __align__(16) unsigned short Ks[128 * 72];   // [key_local][64 k]
    __shared__ __align__(16) unsigned short Vt[64 * VTS];   // [d][key_local 0..151]
    __shared__ __align__(16) unsigned short Ps[4][16][96];  // [wave][q][kk]

    const int h   = blockIdx.y;
    const int q0  = blockIdx.x * 64;
    const int tid = threadIdx.x;

    for (int c = tid; c < 512; c += 256) {
        int row = c >> 3, ch = c & 7;
        *(ushort8v*)&Qs[row * 72 + ch * 8] =
            *(const ushort8v*)&Qp[(size_t)(q0 + row) * 512 + h * 64 + ch * 8];
    }
    for (int c = tid; c < 1024; c += 256) {
        int row = c >> 3, ch = c & 7;
        int g = q0 - 64 + row;
        ushort8v val = {0, 0, 0, 0, 0, 0, 0, 0};
        if (g >= 0)
            val = *(const ushort8v*)&Kp[(size_t)g * 512 + h * 64 + ch * 8];
        *(ushort8v*)&Ks[row * 72 + ch * 8] = val;
    }
    {
        int key = tid >> 1, dh = tid & 1;
        int g = q0 - 64 + key;
        ushort8v vv[4];
        #pragma unroll
        for (int j = 0; j < 4; j++) {
            ushort8v z = {0, 0, 0, 0, 0, 0, 0, 0};
            vv[j] = (g >= 0)
                ? *(const ushort8v*)&Vp[(size_t)g * 512 + h * 64 + dh * 32 + j * 8]
                : z;
        }
        #pragma unroll
        for (int j = 0; j < 4; j++)
            #pragma unroll
            for (int e = 0; e < 8; e++)
                Vt[(dh * 32 + j * 8 + e) * VTS + key] = vv[j][e];
    }
    // zero pad keys 128..151 for all 64 d-rows (deterministic 0*0 tail)
    for (int t = tid; t < 64 * 24; t += 256) {
        int d = t / 24, c = 128 + (t % 24);
        Vt[d * VTS + c] = 0;
    }
    __syncthreads();

    const int lane = tid & 63;
    const int w    = tid >> 6;
    const int lm   = lane & 15;
    const int g16  = lane >> 4;
    const int lk8  = g16 * 8;

    short8 av0 = *(const short8*)&Qs[(w * 16 + lm) * 72 + lk8];
    short8 av1 = *(const short8*)&Qs[(w * 16 + lm) * 72 + 32 + lk8];
    float4v sc[5];
    #pragma unroll
    for (int kt = 0; kt < 5; kt++) {
        const unsigned short* kr = &Ks[(w * 16 + kt * 16 + lm) * 72];
        short8 b0 = *(const short8*)(kr + lk8);
        short8 b1 = *(const short8*)(kr + 32 + lk8);
        float4v a = {0.f, 0.f, 0.f, 0.f};
        a = __builtin_amdgcn_mfma_f32_16x16x32_bf16(av0, b0, a, 0, 0, 0);
        a = __builtin_amdgcn_mfma_f32_16x16x32_bf16(av1, b1, a, 0, 0, 0);
        sc[kt] = a;
    }

    float v[5][4];
    #pragma unroll
    for (int kt = 0; kt < 5; kt++) {
        int kk = kt * 16 + lm;
        int g  = q0 - 64 + w * 16 + kk;
        #pragma unroll
        for (int reg = 0; reg < 4; reg++) {
            int rr = g16 * 4 + reg;
            bool valid = (kk >= rr) && (kk <= rr + 64) && (g >= 0);
            v[kt][reg] = valid
                ? sc[kt][reg] * 0.125f + 0.1f * __expf(-0.1f * (float)(64 + rr - kk))
                : NEGV;
        }
    }

    float mx[4], sm[4];
    #pragma unroll
    for (int reg = 0; reg < 4; reg++) {
        float m = v[0][reg];
        #pragma unroll
        for (int kt = 1; kt < 5; kt++) m = fmaxf(m, v[kt][reg]);
        mx[reg] = m;
    }
    #pragma unroll
    for (int off = 1; off < 16; off <<= 1)
        #pragma unroll
        for (int reg = 0; reg < 4; reg++)
            mx[reg] = fmaxf(mx[reg], __shfl_xor(mx[reg], off));
    float p[5][4];
    #pragma unroll
    for (int reg = 0; reg < 4; reg++) {
        float s = 0.f;
        #pragma unroll
        for (int kt = 0; kt < 5; kt++) {
            float e = __expf(v[kt][reg] - mx[reg]);
            p[kt][reg] = e;
            s += e;
        }
        sm[reg] = s;
    }
    #pragma unroll
    for (int off = 1; off < 16; off <<= 1)
        #pragma unroll
        for (int reg = 0; reg < 4; reg++)
            sm[reg] += __shfl_xor(sm[reg], off);
    #pragma unroll
    for (int reg = 0; reg < 4; reg++) {
        float inv = 1.f / sm[reg];
        #pragma unroll
        for (int kt = 0; kt < 5; kt++) p[kt][reg] *= inv;
    }

    #pragma unroll
    for (int kt = 0; kt < 5; kt++)
        #pragma unroll
        for (int reg = 0; reg < 4; reg++)
            Ps[w][g16 * 4 + reg][kt * 16 + lm] = f2bf(p[kt][reg]);
    #pragma unroll
    for (int reg = 0; reg < 4; reg++)
        Ps[w][g16 * 4 + reg][80 + lm] = 0;

    // Cross-lane LDS RAW: Ps written by rows g16*4+reg, read below by rows lm.
    __syncthreads();

    float4v oacc[4] = {};
    #pragma unroll
    for (int ks = 0; ks < 3; ks++) {
        short8 pa = *(const short8*)&Ps[w][lm][ks * 32 + lk8];
        #pragma unroll
        for (int nt = 0; nt < 4; nt++) {
            short8 vb = *(const short8*)&Vt[(nt * 16 + lm) * VTS + w * 16 + ks * 32 + lk8];
            oacc[nt] = __builtin_amdgcn_mfma_f32_16x16x32_bf16(pa, vb, oacc[nt], 0, 0, 0);
        }
    }

    #pragma unroll
    for (int nt = 0; nt < 4; nt++)
        #pragma unroll
        for (int reg = 0; reg < 4; reg++) {
            int i = q0 + w * 16 + g16 * 4 + reg;
            ctxb[(size_t)i * 512 + h * 64 + nt * 16 + lm] = f2bf(oacc[nt][reg]);
        }

    __syncthreads();

    for (int t = tid; t < 64 * 128; t += 256) {
        int ql = t >> 7, slot = t & 127;
        int i  = q0 + ql;
        float val = 0.f;
        if (q0 == 0) {
            if (slot <= ql) {
                int kk = (ql & 15) + slot + 64 - ql;
                val = bf2f(Ps[ql >> 4][ql & 15][kk]);
            }
        } else if (q0 == SEQ - 64) {
            if (slot <= 64) {
                int kk = (ql & 15) + slot;
                val = bf2f(Ps[ql >> 4][ql & 15][kk]);
            }
        }
        attnw[((size_t)h * SEQ + i) * 2 * WIN + slot] = val;
    }
}

// ---------------------------------------------------------------------------
extern "C" void kernel_launch(void* const* d_in, const int* in_sizes, int n_in,
                              void* d_out, int out_size, void* d_ws, size_t ws_size,
                              hipStream_t stream)
{
    const float* query = (const float*)d_in[0];
    const float* key   = (const float*)d_in[1];
    const float* value = (const float*)d_in[2];
    const float* Wq    = (const float*)d_in[3];
    const float* Wk    = (const float*)d_in[4];
    const float* Wv    = (const float*)d_in[5];
    const float* Wo    = (const float*)d_in[6];
    const float* bo    = (const float*)d_in[7];

    float* out   = (float*)d_out;                 // 2048*512 f32
    float* attnw = out + SEQ * DM;                // 8*2048*128 f32

    unsigned short* qb   = (unsigned short*)d_ws;       // casts of inputs
    unsigned short* kb   = qb  + 1048576;
    unsigned short* vb   = kb  + 1048576;
    unsigned short* wqb  = vb  + 1048576;
    unsigned short* wkb  = wqb + 262144;
    unsigned short* wvb  = wkb + 262144;
    unsigned short* wob  = wvb + 262144;
    unsigned short* Qp   = wob + 262144;                // projected, bf16
    unsigned short* Kp   = Qp  + 1048576;
    unsigned short* Vp   = Kp  + 1048576;
    unsigned short* ctxb = Vp  + 1048576;

    cast7_kernel<<<2048, 256, 0, stream>>>(query, key, value, Wq, Wk, Wv, Wo, qb);

    dim3 g1(SEQ / 128, DM / 128, 3);
    qkv_gemm_kernel<<<g1, 256, 0, stream>>>(qb, kb, vb, wqb, wkb, wvb, Qp, Kp, Vp);

    dim3 g2(SEQ / 64, NHEAD);
    attn_kernel<<<g2, 256, 0, stream>>>(Qp, Kp, Vp, ctxb, attnw);

    dim3 g3(SEQ / 128, DM / 128);
    out_gemm_kernel<<<g3, 256, 0, stream>>>(ctxb, wob, bo, out);
}

// Round 2
// 108.155 us; speedup vs baseline: 1.0592x; 1.0131x over previous
//
#include <hip/hip_runtime.h>
#include <stdint.h>

#define SEQ   2048
#define DM    512
#define NHEAD 8
#define DKH   64
#define WIN   64
#define NEGV  -1000000000.0f

typedef __attribute__((ext_vector_type(8))) short          short8;
typedef __attribute__((ext_vector_type(4))) float          float4v;
typedef __attribute__((ext_vector_type(8))) unsigned short ushort8v;

__device__ __forceinline__ unsigned short f2bf(float x) {
    uint32_t u = __float_as_uint(x);
    uint32_t r = (u + 0x7FFFu + ((u >> 16) & 1u)) >> 16;
    return (unsigned short)r;
}
__device__ __forceinline__ float bf2f(unsigned short u) {
    return __uint_as_float(((uint32_t)u) << 16);
}

// ---------------------------------------------------------------------------
// Unified bf16-MFMA NT GEMM: C[m,n] = sum_k A[m,k]*B[n,k] (+bias[n]).
// A/B may be f32 (cast to bf16 in-register during staging — this fuses the
// old cast7 kernel into the GEMMs) or pre-cast bf16. K fixed at 512, BK=32.
// Reg-staged 2-phase pipeline, 1 barrier per K-step:
//   iter t: ds_read frags buf[t&1] -> MFMA -> ds_write buf[t&1^1] (regs t+1,
//   loaded one full iteration ago) -> issue global loads t+2 -> barrier.
// Writing buf[cur^1] is safe: its last readers finished before the barrier
// that ended iter t-1. Global loads get a whole iteration (~200-400cy) of
// MFMA+ds work to cover L2 latency before their ds_write consumes them.
// ---------------------------------------------------------------------------
template<bool A_F32, bool B_F32, bool BIAS, bool OUT_BF16, int BM, int BN>
__device__ __forceinline__ void gemm_body(const void* __restrict__ Ap,
                                          const void* __restrict__ Bp,
                                          const float* __restrict__ bias,
                                          void* __restrict__ Cv)
{
    __shared__ __align__(16) unsigned short As[2][BM * 32];
    __shared__ __align__(16) unsigned short Bs[2][BN * 32];

    constexpr int HA = BM / 64;     // staging chunks per thread for A
    constexpr int HB = BN / 64;
    constexpr int FM = BM / 32;     // 16x16 frags per wave (2x2 wave grid)
    constexpr int FN = BN / 32;

    const int tid  = threadIdx.x;
    const int m0   = blockIdx.x * BM;
    const int n0   = blockIdx.y * BN;
    const int lane = tid & 63;
    const int wave = tid >> 6;
    const int wm   = (wave >> 1) * (BM / 2);
    const int wn   = (wave & 1) * (BN / 2);
    const int lm   = lane & 15;
    const int lk   = (lane >> 4) * 8;

    float4v acc[FM][FN] = {};

    // 1-deep per-thread staging registers
    float4   raf[HA][2]; ushort8v rab[HA];
    float4   rbf[HB][2]; ushort8v rbb[HB];

    auto load_regs = [&](int k0) {
        #pragma unroll
        for (int h = 0; h < HA; h++) {
            int c = tid + h * 256;
            int r = c >> 2, kc = (c & 3) * 8;
            if constexpr (A_F32) {
                const float* p = (const float*)Ap + (size_t)(m0 + r) * 512 + k0 + kc;
                raf[h][0] = *(const float4*)p;
                raf[h][1] = *(const float4*)(p + 4);
            } else {
                rab[h] = *(const ushort8v*)((const unsigned short*)Ap +
                                            (size_t)(m0 + r) * 512 + k0 + kc);
            }
        }
        #pragma unroll
        for (int h = 0; h < HB; h++) {
            int c = tid + h * 256;
            int r = c >> 2, kc = (c & 3) * 8;
            if constexpr (B_F32) {
                const float* p = (const float*)Bp + (size_t)(n0 + r) * 512 + k0 + kc;
                rbf[h][0] = *(const float4*)p;
                rbf[h][1] = *(const float4*)(p + 4);
            } else {
                rbb[h] = *(const ushort8v*)((const unsigned short*)Bp +
                                            (size_t)(n0 + r) * 512 + k0 + kc);
            }
        }
    };
    auto store_lds = [&](int buf) {
        #pragma unroll
        for (int h = 0; h < HA; h++) {
            int c = tid + h * 256;
            int r = c >> 2, kc = (c & 3) * 8;
            ushort8v o;
            if constexpr (A_F32) {
                o[0] = f2bf(raf[h][0].x); o[1] = f2bf(raf[h][0].y);
                o[2] = f2bf(raf[h][0].z); o[3] = f2bf(raf[h][0].w);
                o[4] = f2bf(raf[h][1].x); o[5] = f2bf(raf[h][1].y);
                o[6] = f2bf(raf[h][1].z); o[7] = f2bf(raf[h][1].w);
            } else {
                o = rab[h];
            }
            *(ushort8v*)&As[buf][r * 32 + kc] = o;
        }
        #pragma unroll
        for (int h = 0; h < HB; h++) {
            int c = tid + h * 256;
            int r = c >> 2, kc = (c & 3) * 8;
            ushort8v o;
            if constexpr (B_F32) {
                o[0] = f2bf(rbf[h][0].x); o[1] = f2bf(rbf[h][0].y);
                o[2] = f2bf(rbf[h][0].z); o[3] = f2bf(rbf[h][0].w);
                o[4] = f2bf(rbf[h][1].x); o[5] = f2bf(rbf[h][1].y);
                o[6] = f2bf(rbf[h][1].z); o[7] = f2bf(rbf[h][1].w);
            } else {
                o = rbb[h];
            }
            *(ushort8v*)&Bs[buf][r * 32 + kc] = o;
        }
    };

    // prologue: stage t0, issue t1
    load_regs(0);
    store_lds(0);
    load_regs(32);
    __syncthreads();

    for (int t = 0; t < 16; ++t) {
        const int cur = t & 1;
        short8 av[FM], bv[FN];
        #pragma unroll
        for (int mt = 0; mt < FM; mt++)
            av[mt] = *(const short8*)&As[cur][(wm + mt * 16 + lm) * 32 + lk];
        #pragma unroll
        for (int nt = 0; nt < FN; nt++)
            bv[nt] = *(const short8*)&Bs[cur][(wn + nt * 16 + lm) * 32 + lk];
        #pragma unroll
        for (int mt = 0; mt < FM; mt++)
            #pragma unroll
            for (int nt = 0; nt < FN; nt++)
                acc[mt][nt] = __builtin_amdgcn_mfma_f32_16x16x32_bf16(
                    av[mt], bv[nt], acc[mt][nt], 0, 0, 0);
        if (t < 15) {
            store_lds(cur ^ 1);             // regs for t+1 (vmcnt waited here)
            if (t < 14) load_regs((t + 2) * 32);
        }
        __syncthreads();
    }

    const int r0 = (lane >> 4) * 4;
    const int cn = lane & 15;
    #pragma unroll
    for (int nt = 0; nt < FN; nt++) {
        int gcol = n0 + wn + nt * 16 + cn;
        float b = BIAS ? bias[gcol] : 0.f;
        #pragma unroll
        for (int mt = 0; mt < FM; mt++) {
            int grow = m0 + wm + mt * 16 + r0;
            #pragma unroll
            for (int reg = 0; reg < 4; reg++) {
                float val = acc[mt][nt][reg] + b;
                if (OUT_BF16)
                    ((unsigned short*)Cv)[(size_t)(grow + reg) * 512 + gcol] = f2bf(val);
                else
                    ((float*)Cv)[(size_t)(grow + reg) * 512 + gcol] = val;
            }
        }
    }
}

__global__ __launch_bounds__(256)
void qkv_gemm_kernel(const float* __restrict__ q, const float* __restrict__ k,
                     const float* __restrict__ v, const float* __restrict__ wq,
                     const float* __restrict__ wk, const float* __restrict__ wv,
                     unsigned short* __restrict__ Qp, unsigned short* __restrict__ Kp,
                     unsigned short* __restrict__ Vp)
{
    const float *A, *B; unsigned short* C;
    if (blockIdx.z == 0)      { A = q; B = wq; C = Qp; }
    else if (blockIdx.z == 1) { A = k; B = wk; C = Kp; }
    else                      { A = v; B = wv; C = Vp; }
    gemm_body<true, true, false, true, 128, 128>(A, B, nullptr, C);
}

__global__ __launch_bounds__(256)
void out_gemm_kernel(const unsigned short* __restrict__ ctxb,
                     const float* __restrict__ wo,
                     const float* __restrict__ bo, float* __restrict__ out)
{
    gemm_body<false, true, true, false, 128, 64>(ctxb, wo, bo, out);
}

// ---------------------------------------------------------------------------
// MFMA windowed attention. Block = 64 queries x 1 head, 256 thr = 4 waves.
// Wave w owns queries q0+w*16..+15 and local key rows w*16..w*16+79.
// Vt stride = 152 ushorts (304B = 19x16B aligned; 2-way bank alias = free).
// Keys 128..151 explicitly zeroed: wave 3's PV reads reach key 143 with
// zero P operands — uninit LDS there was the r4/r5 NaN source (0*NaN=NaN).
// ---------------------------------------------------------------------------
#define VTS 152

__global__ __launch_bounds__(256)
void attn_kernel(const unsigned short* __restrict__ Qp,
                 const unsigned short* __restrict__ Kp,
                 const unsigned short* __restrict__ Vp,
                 unsigned short* __restrict__ ctxb,
                 float* __restrict__ attnw)
{
    __shared__ __align__(16) unsigned short Qs[64 * 72];    // [q_local][64 k]
    __shared__ __align__(16) unsigned short Ks[128 * 72];   // [key_local][64 k]
    __shared__ __align__(16) unsigned short Vt[64 * VTS];   // [d][key_local 0..151]
    __shared__ __align__(16) unsigned short Ps[4][16][96];  // [wave][q][kk]

    const int h   = blockIdx.y;
    const int q0  = blockIdx.x * 64;
    const int tid = threadIdx.x;

    for (int c = tid; c < 512; c += 256) {
        int row = c >> 3, ch = c & 7;
        *(ushort8v*)&Qs[row * 72 + ch * 8] =
            *(const ushort8v*)&Qp[(size_t)(q0 + row) * 512 + h * 64 + ch * 8];
    }
    for (int c = tid; c < 1024; c += 256) {
        int row = c >> 3, ch = c & 7;
        int g = q0 - 64 + row;
        ushort8v val = {0, 0, 0, 0, 0, 0, 0, 0};
        if (g >= 0)
            val = *(const ushort8v*)&Kp[(size_t)g * 512 + h * 64 + ch * 8];
        *(ushort8v*)&Ks[row * 72 + ch * 8] = val;
    }
    {
        int key = tid >> 1, dh = tid & 1;
        int g = q0 - 64 + key;
        ushort8v vv[4];
        #pragma unroll
        for (int j = 0; j < 4; j++) {
            ushort8v z = {0, 0, 0, 0, 0, 0, 0, 0};
            vv[j] = (g >= 0)
                ? *(const ushort8v*)&Vp[(size_t)g * 512 + h * 64 + dh * 32 + j * 8]
                : z;
        }
        #pragma unroll
        for (int j = 0; j < 4; j++)
            #pragma unroll
            for (int e = 0; e < 8; e++)
                Vt[(dh * 32 + j * 8 + e) * VTS + key] = vv[j][e];
    }
    // zero pad keys 128..151 for all 64 d-rows (deterministic 0*0 tail)
    for (int t = tid; t < 64 * 24; t += 256) {
        int d = t / 24, c = 128 + (t % 24);
        Vt[d * VTS + c] = 0;
    }
    __syncthreads();

    const int lane = tid & 63;
    const int w    = tid >> 6;
    const int lm   = lane & 15;
    const int g16  = lane >> 4;
    const int lk8  = g16 * 8;

    short8 av0 = *(const short8*)&Qs[(w * 16 + lm) * 72 + lk8];
    short8 av1 = *(const short8*)&Qs[(w * 16 + lm) * 72 + 32 + lk8];
    float4v sc[5];
    #pragma unroll
    for (int kt = 0; kt < 5; kt++) {
        const unsigned short* kr = &Ks[(w * 16 + kt * 16 + lm) * 72];
        short8 b0 = *(const short8*)(kr + lk8);
        short8 b1 = *(const short8*)(kr + 32 + lk8);
        float4v a = {0.f, 0.f, 0.f, 0.f};
        a = __builtin_amdgcn_mfma_f32_16x16x32_bf16(av0, b0, a, 0, 0, 0);
        a = __builtin_amdgcn_mfma_f32_16x16x32_bf16(av1, b1, a, 0, 0, 0);
        sc[kt] = a;
    }

    float v[5][4];
    #pragma unroll
    for (int kt = 0; kt < 5; kt++) {
        int kk = kt * 16 + lm;
        int g  = q0 - 64 + w * 16 + kk;
        #pragma unroll
        for (int reg = 0; reg < 4; reg++) {
            int rr = g16 * 4 + reg;
            bool valid = (kk >= rr) && (kk <= rr + 64) && (g >= 0);
            v[kt][reg] = valid
                ? sc[kt][reg] * 0.125f + 0.1f * __expf(-0.1f * (float)(64 + rr - kk))
                : NEGV;
        }
    }

    float mx[4], sm[4];
    #pragma unroll
    for (int reg = 0; reg < 4; reg++) {
        float m = v[0][reg];
        #pragma unroll
        for (int kt = 1; kt < 5; kt++) m = fmaxf(m, v[kt][reg]);
        mx[reg] = m;
    }
    #pragma unroll
    for (int off = 1; off < 16; off <<= 1)
        #pragma unroll
        for (int reg = 0; reg < 4; reg++)
            mx[reg] = fmaxf(mx[reg], __shfl_xor(mx[reg], off));
    float p[5][4];
    #pragma unroll
    for (int reg = 0; reg < 4; reg++) {
        float s = 0.f;
        #pragma unroll
        for (int kt = 0; kt < 5; kt++) {
            float e = __expf(v[kt][reg] - mx[reg]);
            p[kt][reg] = e;
            s += e;
        }
        sm[reg] = s;
    }
    #pragma unroll
    for (int off = 1; off < 16; off <<= 1)
        #pragma unroll
        for (int reg = 0; reg < 4; reg++)
            sm[reg] += __shfl_xor(sm[reg], off);
    #pragma unroll
    for (int reg = 0; reg < 4; reg++) {
        float inv = 1.f / sm[reg];
        #pragma unroll
        for (int kt = 0; kt < 5; kt++) p[kt][reg] *= inv;
    }

    #pragma unroll
    for (int kt = 0; kt < 5; kt++)
        #pragma unroll
        for (int reg = 0; reg < 4; reg++)
            Ps[w][g16 * 4 + reg][kt * 16 + lm] = f2bf(p[kt][reg]);
    #pragma unroll
    for (int reg = 0; reg < 4; reg++)
        Ps[w][g16 * 4 + reg][80 + lm] = 0;

    // Cross-lane LDS RAW: Ps written by rows g16*4+reg, read below by rows lm.
    __syncthreads();

    float4v oacc[4] = {};
    #pragma unroll
    for (int ks = 0; ks < 3; ks++) {
        short8 pa = *(const short8*)&Ps[w][lm][ks * 32 + lk8];
        #pragma unroll
        for (int nt = 0; nt < 4; nt++) {
            short8 vb = *(const short8*)&Vt[(nt * 16 + lm) * VTS + w * 16 + ks * 32 + lk8];
            oacc[nt] = __builtin_amdgcn_mfma_f32_16x16x32_bf16(pa, vb, oacc[nt], 0, 0, 0);
        }
    }

    #pragma unroll
    for (int nt = 0; nt < 4; nt++)
        #pragma unroll
        for (int reg = 0; reg < 4; reg++) {
            int i = q0 + w * 16 + g16 * 4 + reg;
            ctxb[(size_t)i * 512 + h * 64 + nt * 16 + lm] = f2bf(oacc[nt][reg]);
        }

    __syncthreads();

    // attnw: only the first and last 64-query blocks have nonzero rows;
    // vectorized float4 stores (8 floats per work item).
    for (int t = tid; t < 1024; t += 256) {
        int ql = t >> 4;               // 0..63
        int s0 = (t & 15) * 8;         // slot base
        int i  = q0 + ql;
        float4 v0 = {0.f, 0.f, 0.f, 0.f}, v1 = {0.f, 0.f, 0.f, 0.f};
        if (q0 == 0) {
            #pragma unroll
            for (int e = 0; e < 8; e++) {
                int slot = s0 + e;
                if (slot <= ql) {
                    int kk = (ql & 15) + slot + 64 - ql;
                    float vv = bf2f(Ps[ql >> 4][ql & 15][kk]);
                    if (e < 4) ((float*)&v0)[e] = vv; else ((float*)&v1)[e - 4] = vv;
                }
            }
        } else if (q0 == SEQ - 64) {
            #pragma unroll
            for (int e = 0; e < 8; e++) {
                int slot = s0 + e;
                if (slot <= 64) {
                    int kk = (ql & 15) + slot;
                    float vv = bf2f(Ps[ql >> 4][ql & 15][kk]);
                    if (e < 4) ((float*)&v0)[e] = vv; else ((float*)&v1)[e - 4] = vv;
                }
            }
        }
        float* dst = &attnw[((size_t)h * SEQ + i) * 2 * WIN + s0];
        *(float4*)dst       = v0;
        *(float4*)(dst + 4) = v1;
    }
}

// ---------------------------------------------------------------------------
extern "C" void kernel_launch(void* const* d_in, const int* in_sizes, int n_in,
                              void* d_out, int out_size, void* d_ws, size_t ws_size,
                              hipStream_t stream)
{
    const float* query = (const float*)d_in[0];
    const float* key   = (const float*)d_in[1];
    const float* value = (const float*)d_in[2];
    const float* Wq    = (const float*)d_in[3];
    const float* Wk    = (const float*)d_in[4];
    const float* Wv    = (const float*)d_in[5];
    const float* Wo    = (const float*)d_in[6];
    const float* bo    = (const float*)d_in[7];

    float* out   = (float*)d_out;                 // 2048*512 f32
    float* attnw = out + SEQ * DM;                // 8*2048*128 f32

    unsigned short* Qp   = (unsigned short*)d_ws;       // projected, bf16
    unsigned short* Kp   = Qp + 1048576;
    unsigned short* Vp   = Kp + 1048576;
    unsigned short* ctxb = Vp + 1048576;

    dim3 g1(SEQ / 128, DM / 128, 3);
    qkv_gemm_kernel<<<g1, 256, 0, stream>>>(query, key, value, Wq, Wk, Wv, Qp, Kp, Vp);

    dim3 g2(SEQ / 64, NHEAD);
    attn_kernel<<<g2, 256, 0, stream>>>(Qp, Kp, Vp, ctxb, attnw);

    dim3 g3(SEQ / 128, DM / 64);
    out_gemm_kernel<<<g3, 256, 0, stream>>>(ctxb, Wo, bo, out);
}

// Round 3
// 103.023 us; speedup vs baseline: 1.1119x; 1.0498x over previous
//
#include <hip/hip_runtime.h>
#include <stdint.h>

#define SEQ   2048
#define DM    512
#define NHEAD 8
#define DKH   64
#define WIN   64
#define NEGV  -1000000000.0f

typedef __attribute__((ext_vector_type(8))) short          short8;
typedef __attribute__((ext_vector_type(4))) float          float4v;
typedef __attribute__((ext_vector_type(8))) unsigned short ushort8v;

__device__ __forceinline__ unsigned short f2bf(float x) {
    uint32_t u = __float_as_uint(x);
    uint32_t r = (u + 0x7FFFu + ((u >> 16) & 1u)) >> 16;
    return (unsigned short)r;
}
__device__ __forceinline__ float bf2f(unsigned short u) {
    return __uint_as_float(((uint32_t)u) << 16);
}

// ---------------------------------------------------------------------------
// Unified bf16-MFMA NT GEMM: C[m,n] = sum_k A[m,k]*B[n,k] (+bias[n]).
// A/B may be f32 (cast to bf16 in-register during staging) or bf16.
// K fixed at 512, BK=32. Reg-staged 2-phase pipeline, 1 barrier per K-step.
//
// Tile 64x64 (was 128x128): these GEMMs are LATENCY-bound (2048x512x512 is
// deep in m102's small-shape regime), so the lever is blocks/CU, not
// per-block arithmetic intensity. 64^2 gives qkv 768 blocks (~3/CU) and out
// 256 blocks (full chip) -> cross-block wave overlap absorbs the per-K-step
// barrier/lgkm stalls that a single resident block must eat serially.
// LDS 16 KB/block, acc 16 VGPR -> occupancy is block-count-limited.
// ---------------------------------------------------------------------------
template<bool A_F32, bool B_F32, bool BIAS, bool OUT_BF16, int BM, int BN>
__device__ __forceinline__ void gemm_body(const void* __restrict__ Ap,
                                          const void* __restrict__ Bp,
                                          const float* __restrict__ bias,
                                          void* __restrict__ Cv)
{
    __shared__ __align__(16) unsigned short As[2][BM * 32];
    __shared__ __align__(16) unsigned short Bs[2][BN * 32];

    constexpr int HA = (BM * 32) / (256 * 8);   // staging chunks/thread for A
    constexpr int HB = (BN * 32) / (256 * 8);
    constexpr int FM = BM / 32;                 // 16x16 frags per wave
    constexpr int FN = BN / 32;

    const int tid  = threadIdx.x;
    const int m0   = blockIdx.x * BM;
    const int n0   = blockIdx.y * BN;
    const int lane = tid & 63;
    const int wave = tid >> 6;
    const int wm   = (wave >> 1) * (BM / 2);
    const int wn   = (wave & 1) * (BN / 2);
    const int lm   = lane & 15;
    const int lk   = (lane >> 4) * 8;

    float4v acc[FM][FN] = {};

    // 1-deep per-thread staging registers
    float4   raf[HA][2]; ushort8v rab[HA];
    float4   rbf[HB][2]; ushort8v rbb[HB];

    auto load_regs = [&](int k0) {
        #pragma unroll
        for (int h = 0; h < HA; h++) {
            int c = tid + h * 256;
            int r = c >> 2, kc = (c & 3) * 8;
            if constexpr (A_F32) {
                const float* p = (const float*)Ap + (size_t)(m0 + r) * 512 + k0 + kc;
                raf[h][0] = *(const float4*)p;
                raf[h][1] = *(const float4*)(p + 4);
            } else {
                rab[h] = *(const ushort8v*)((const unsigned short*)Ap +
                                            (size_t)(m0 + r) * 512 + k0 + kc);
            }
        }
        #pragma unroll
        for (int h = 0; h < HB; h++) {
            int c = tid + h * 256;
            int r = c >> 2, kc = (c & 3) * 8;
            if constexpr (B_F32) {
                const float* p = (const float*)Bp + (size_t)(n0 + r) * 512 + k0 + kc;
                rbf[h][0] = *(const float4*)p;
                rbf[h][1] = *(const float4*)(p + 4);
            } else {
                rbb[h] = *(const ushort8v*)((const unsigned short*)Bp +
                                            (size_t)(n0 + r) * 512 + k0 + kc);
            }
        }
    };
    auto store_lds = [&](int buf) {
        #pragma unroll
        for (int h = 0; h < HA; h++) {
            int c = tid + h * 256;
            int r = c >> 2, kc = (c & 3) * 8;
            ushort8v o;
            if constexpr (A_F32) {
                o[0] = f2bf(raf[h][0].x); o[1] = f2bf(raf[h][0].y);
                o[2] = f2bf(raf[h][0].z); o[3] = f2bf(raf[h][0].w);
                o[4] = f2bf(raf[h][1].x); o[5] = f2bf(raf[h][1].y);
                o[6] = f2bf(raf[h][1].z); o[7] = f2bf(raf[h][1].w);
            } else {
                o = rab[h];
            }
            *(ushort8v*)&As[buf][r * 32 + kc] = o;
        }
        #pragma unroll
        for (int h = 0; h < HB; h++) {
            int c = tid + h * 256;
            int r = c >> 2, kc = (c & 3) * 8;
            ushort8v o;
            if constexpr (B_F32) {
                o[0] = f2bf(rbf[h][0].x); o[1] = f2bf(rbf[h][0].y);
                o[2] = f2bf(rbf[h][0].z); o[3] = f2bf(rbf[h][0].w);
                o[4] = f2bf(rbf[h][1].x); o[5] = f2bf(rbf[h][1].y);
                o[6] = f2bf(rbf[h][1].z); o[7] = f2bf(rbf[h][1].w);
            } else {
                o = rbb[h];
            }
            *(ushort8v*)&Bs[buf][r * 32 + kc] = o;
        }
    };

    // prologue: stage t0, issue t1
    load_regs(0);
    store_lds(0);
    load_regs(32);
    __syncthreads();

    for (int t = 0; t < 16; ++t) {
        const int cur = t & 1;
        short8 av[FM], bv[FN];
        #pragma unroll
        for (int mt = 0; mt < FM; mt++)
            av[mt] = *(const short8*)&As[cur][(wm + mt * 16 + lm) * 32 + lk];
        #pragma unroll
        for (int nt = 0; nt < FN; nt++)
            bv[nt] = *(const short8*)&Bs[cur][(wn + nt * 16 + lm) * 32 + lk];
        #pragma unroll
        for (int mt = 0; mt < FM; mt++)
            #pragma unroll
            for (int nt = 0; nt < FN; nt++)
                acc[mt][nt] = __builtin_amdgcn_mfma_f32_16x16x32_bf16(
                    av[mt], bv[nt], acc[mt][nt], 0, 0, 0);
        if (t < 15) {
            store_lds(cur ^ 1);             // regs for t+1 (vmcnt waited here)
            if (t < 14) load_regs((t + 2) * 32);
        }
        __syncthreads();
    }

    const int r0 = (lane >> 4) * 4;
    const int cn = lane & 15;
    #pragma unroll
    for (int nt = 0; nt < FN; nt++) {
        int gcol = n0 + wn + nt * 16 + cn;
        float b = BIAS ? bias[gcol] : 0.f;
        #pragma unroll
        for (int mt = 0; mt < FM; mt++) {
            int grow = m0 + wm + mt * 16 + r0;
            #pragma unroll
            for (int reg = 0; reg < 4; reg++) {
                float val = acc[mt][nt][reg] + b;
                if (OUT_BF16)
                    ((unsigned short*)Cv)[(size_t)(grow + reg) * 512 + gcol] = f2bf(val);
                else
                    ((float*)Cv)[(size_t)(grow + reg) * 512 + gcol] = val;
            }
        }
    }
}

__global__ __launch_bounds__(256)
void qkv_gemm_kernel(const float* __restrict__ q, const float* __restrict__ k,
                     const float* __restrict__ v, const float* __restrict__ wq,
                     const float* __restrict__ wk, const float* __restrict__ wv,
                     unsigned short* __restrict__ Qp, unsigned short* __restrict__ Kp,
                     unsigned short* __restrict__ Vp)
{
    const float *A, *B; unsigned short* C;
    if (blockIdx.z == 0)      { A = q; B = wq; C = Qp; }
    else if (blockIdx.z == 1) { A = k; B = wk; C = Kp; }
    else                      { A = v; B = wv; C = Vp; }
    gemm_body<true, true, false, true, 64, 64>(A, B, nullptr, C);
}

__global__ __launch_bounds__(256)
void out_gemm_kernel(const unsigned short* __restrict__ ctxb,
                     const float* __restrict__ wo,
                     const float* __restrict__ bo, float* __restrict__ out)
{
    gemm_body<false, true, true, false, 64, 64>(ctxb, wo, bo, out);
}

// ---------------------------------------------------------------------------
// MFMA windowed attention. Block = 64 queries x 1 head, 256 thr = 4 waves.
// Wave w owns queries q0+w*16..+15 and local key rows w*16..w*16+79.
// Vt stride = 152 ushorts (304B = 19x16B aligned; 2-way bank alias = free).
// Keys 128..151 explicitly zeroed: wave 3's PV reads reach key 143 with
// zero P operands — uninit LDS there was the r4/r5 NaN source (0*NaN=NaN).
// ---------------------------------------------------------------------------
#define VTS 152

__global__ __launch_bounds__(256)
void attn_kernel(const unsigned short* __restrict__ Qp,
                 const unsigned short* __restrict__ Kp,
                 const unsigned short* __restrict__ Vp,
                 unsigned short* __restrict__ ctxb,
                 float* __restrict__ attnw)
{
    __shared__ __align__(16) unsigned short Qs[64 * 72];    // [q_local][64 k]
    __shared__ __align__(16) unsigned short Ks[128 * 72];   // [key_local][64 k]
    __shared__ __align__(16) unsigned short Vt[64 * VTS];   // [d][key_local 0..151]
    __shared__ __align__(16) unsigned short Ps[4][16][96];  // [wave][q][kk]

    const int h   = blockIdx.y;
    const int q0  = blockIdx.x * 64;
    const int tid = threadIdx.x;

    for (int c = tid; c < 512; c += 256) {
        int row = c >> 3, ch = c & 7;
        *(ushort8v*)&Qs[row * 72 + ch * 8] =
            *(const ushort8v*)&Qp[(size_t)(q0 + row) * 512 + h * 64 + ch * 8];
    }
    for (int c = tid; c < 1024; c += 256) {
        int row = c >> 3, ch = c & 7;
        int g = q0 - 64 + row;
        ushort8v val = {0, 0, 0, 0, 0, 0, 0, 0};
        if (g >= 0)
            val = *(const ushort8v*)&Kp[(size_t)g * 512 + h * 64 + ch * 8];
        *(ushort8v*)&Ks[row * 72 + ch * 8] = val;
    }
    {
        int key = tid >> 1, dh = tid & 1;
        int g = q0 - 64 + key;
        ushort8v vv[4];
        #pragma unroll
        for (int j = 0; j < 4; j++) {
            ushort8v z = {0, 0, 0, 0, 0, 0, 0, 0};
            vv[j] = (g >= 0)
                ? *(const ushort8v*)&Vp[(size_t)g * 512 + h * 64 + dh * 32 + j * 8]
                : z;
        }
        #pragma unroll
        for (int j = 0; j < 4; j++)
            #pragma unroll
            for (int e = 0; e < 8; e++)
                Vt[(dh * 32 + j * 8 + e) * VTS + key] = vv[j][e];
    }
    // zero pad keys 128..151 for all 64 d-rows (deterministic 0*0 tail)
    for (int t = tid; t < 64 * 24; t += 256) {
        int d = t / 24, c = 128 + (t % 24);
        Vt[d * VTS + c] = 0;
    }
    __syncthreads();

    const int lane = tid & 63;
    const int w    = tid >> 6;
    const int lm   = lane & 15;
    const int g16  = lane >> 4;
    const int lk8  = g16 * 8;

    short8 av0 = *(const short8*)&Qs[(w * 16 + lm) * 72 + lk8];
    short8 av1 = *(const short8*)&Qs[(w * 16 + lm) * 72 + 32 + lk8];
    float4v sc[5];
    #pragma unroll
    for (int kt = 0; kt < 5; kt++) {
        const unsigned short* kr = &Ks[(w * 16 + kt * 16 + lm) * 72];
        short8 b0 = *(const short8*)(kr + lk8);
        short8 b1 = *(const short8*)(kr + 32 + lk8);
        float4v a = {0.f, 0.f, 0.f, 0.f};
        a = __builtin_amdgcn_mfma_f32_16x16x32_bf16(av0, b0, a, 0, 0, 0);
        a = __builtin_amdgcn_mfma_f32_16x16x32_bf16(av1, b1, a, 0, 0, 0);
        sc[kt] = a;
    }

    float v[5][4];
    #pragma unroll
    for (int kt = 0; kt < 5; kt++) {
        int kk = kt * 16 + lm;
        int g  = q0 - 64 + w * 16 + kk;
        #pragma unroll
        for (int reg = 0; reg < 4; reg++) {
            int rr = g16 * 4 + reg;
            bool valid = (kk >= rr) && (kk <= rr + 64) && (g >= 0);
            v[kt][reg] = valid
                ? sc[kt][reg] * 0.125f + 0.1f * __expf(-0.1f * (float)(64 + rr - kk))
                : NEGV;
        }
    }

    float mx[4], sm[4];
    #pragma unroll
    for (int reg = 0; reg < 4; reg++) {
        float m = v[0][reg];
        #pragma unroll
        for (int kt = 1; kt < 5; kt++) m = fmaxf(m, v[kt][reg]);
        mx[reg] = m;
    }
    #pragma unroll
    for (int off = 1; off < 16; off <<= 1)
        #pragma unroll
        for (int reg = 0; reg < 4; reg++)
            mx[reg] = fmaxf(mx[reg], __shfl_xor(mx[reg], off));
    float p[5][4];
    #pragma unroll
    for (int reg = 0; reg < 4; reg++) {
        float s = 0.f;
        #pragma unroll
        for (int kt = 0; kt < 5; kt++) {
            float e = __expf(v[kt][reg] - mx[reg]);
            p[kt][reg] = e;
            s += e;
        }
        sm[reg] = s;
    }
    #pragma unroll
    for (int off = 1; off < 16; off <<= 1)
        #pragma unroll
        for (int reg = 0; reg < 4; reg++)
            sm[reg] += __shfl_xor(sm[reg], off);
    #pragma unroll
    for (int reg = 0; reg < 4; reg++) {
        float inv = 1.f / sm[reg];
        #pragma unroll
        for (int kt = 0; kt < 5; kt++) p[kt][reg] *= inv;
    }

    #pragma unroll
    for (int kt = 0; kt < 5; kt++)
        #pragma unroll
        for (int reg = 0; reg < 4; reg++)
            Ps[w][g16 * 4 + reg][kt * 16 + lm] = f2bf(p[kt][reg]);
    #pragma unroll
    for (int reg = 0; reg < 4; reg++)
        Ps[w][g16 * 4 + reg][80 + lm] = 0;

    // Cross-lane LDS RAW: Ps written by rows g16*4+reg, read below by rows lm.
    __syncthreads();

    float4v oacc[4] = {};
    #pragma unroll
    for (int ks = 0; ks < 3; ks++) {
        short8 pa = *(const short8*)&Ps[w][lm][ks * 32 + lk8];
        #pragma unroll
        for (int nt = 0; nt < 4; nt++) {
            short8 vb = *(const short8*)&Vt[(nt * 16 + lm) * VTS + w * 16 + ks * 32 + lk8];
            oacc[nt] = __builtin_amdgcn_mfma_f32_16x16x32_bf16(pa, vb, oacc[nt], 0, 0, 0);
        }
    }

    #pragma unroll
    for (int nt = 0; nt < 4; nt++)
        #pragma unroll
        for (int reg = 0; reg < 4; reg++) {
            int i = q0 + w * 16 + g16 * 4 + reg;
            ctxb[(size_t)i * 512 + h * 64 + nt * 16 + lm] = f2bf(oacc[nt][reg]);
        }

    __syncthreads();

    // attnw: only the first and last 64-query blocks have nonzero rows;
    // vectorized float4 stores (8 floats per work item).
    for (int t = tid; t < 1024; t += 256) {
        int ql = t >> 4;               // 0..63
        int s0 = (t & 15) * 8;         // slot base
        int i  = q0 + ql;
        float4 v0 = {0.f, 0.f, 0.f, 0.f}, v1 = {0.f, 0.f, 0.f, 0.f};
        if (q0 == 0) {
            #pragma unroll
            for (int e = 0; e < 8; e++) {
                int slot = s0 + e;
                if (slot <= ql) {
                    int kk = (ql & 15) + slot + 64 - ql;
                    float vv = bf2f(Ps[ql >> 4][ql & 15][kk]);
                    if (e < 4) ((float*)&v0)[e] = vv; else ((float*)&v1)[e - 4] = vv;
                }
            }
        } else if (q0 == SEQ - 64) {
            #pragma unroll
            for (int e = 0; e < 8; e++) {
                int slot = s0 + e;
                if (slot <= 64) {
                    int kk = (ql & 15) + slot;
                    float vv = bf2f(Ps[ql >> 4][ql & 15][kk]);
                    if (e < 4) ((float*)&v0)[e] = vv; else ((float*)&v1)[e - 4] = vv;
                }
            }
        }
        float* dst = &attnw[((size_t)h * SEQ + i) * 2 * WIN + s0];
        *(float4*)dst       = v0;
        *(float4*)(dst + 4) = v1;
    }
}

// ---------------------------------------------------------------------------
extern "C" void kernel_launch(void* const* d_in, const int* in_sizes, int n_in,
                              void* d_out, int out_size, void* d_ws, size_t ws_size,
                              hipStream_t stream)
{
    const float* query = (const float*)d_in[0];
    const float* key   = (const float*)d_in[1];
    const float* value = (const float*)d_in[2];
    const float* Wq    = (const float*)d_in[3];
    const float* Wk    = (const float*)d_in[4];
    const float* Wv    = (const float*)d_in[5];
    const float* Wo    = (const float*)d_in[6];
    const float* bo    = (const float*)d_in[7];

    float* out   = (float*)d_out;                 // 2048*512 f32
    float* attnw = out + SEQ * DM;                // 8*2048*128 f32

    unsigned short* Qp   = (unsigned short*)d_ws;       // projected, bf16
    unsigned short* Kp   = Qp + 1048576;
    unsigned short* Vp   = Kp + 1048576;
    unsigned short* ctxb = Vp + 1048576;

    dim3 g1(SEQ / 64, DM / 64, 3);
    qkv_gemm_kernel<<<g1, 256, 0, stream>>>(query, key, value, Wq, Wk, Wv, Qp, Kp, Vp);

    dim3 g2(SEQ / 64, NHEAD);
    attn_kernel<<<g2, 256, 0, stream>>>(Qp, Kp, Vp, ctxb, attnw);

    dim3 g3(SEQ / 64, DM / 64);
    out_gemm_kernel<<<g3, 256, 0, stream>>>(ctxb, Wo, bo, out);
}